// Round 1
// baseline (602.970 us; speedup 1.0000x reference)
//
#include <hip/hip_runtime.h>
#include <hip/hip_bf16.h>

// Bahdanau attention, restructured:
//   tanh_in[b,t,k] = e[b,t,:]@(U@Wa) + cvec[b,k]   (one 131072x512x512 bf16 GEMM)
//   cij[b,t] = sum_k tanh(tanh_in)*V[k]            (fused epilogue, no [B,T,H] tensor)
//   alphas = softmax(cij); out = sum_t alphas*e
// Shapes: B=32 T=4096 D=512 H=512.

#define BB 32
#define TT 4096
#define DD 512
#define HH 512
#define MM (BB * TT)   // 131072 flattened rows

typedef short s16x8 __attribute__((ext_vector_type(8)));
typedef float f32x4 __attribute__((ext_vector_type(4)));

union FU { float f; unsigned u; };

// truncate two f32 -> packed bf16 pair (lo=a, hi=b). Same error variance as RNE,
// zero net bias for sign-symmetric data; ~1.5 VALU ops/elem (compiler fuses to v_perm).
static __device__ __forceinline__ unsigned pack_bf16_trunc(float a, float b) {
    FU ua, ub; ua.f = a; ub.f = b;
    return (ua.u >> 16) | (ub.u & 0xffff0000u);
}

// RNE f32->bf16 (used only in tiny precompute kernel; better precision for B operand)
static __device__ __forceinline__ unsigned short f2bf_rne(float x) {
    FU v; v.f = x;
    unsigned u = v.u;
    u = u + 0x7fffu + ((u >> 16) & 1u);
    return (unsigned short)(u >> 16);
}

static __device__ __forceinline__ float tanh_fast(float x) {
    // tanh(x) = 1 - 2/(exp(2x)+1); exp->v_exp, rcp->v_rcp. Handles +-inf correctly.
    float e = __expf(2.0f * x);
    return 1.0f - 2.0f * __builtin_amdgcn_rcpf(e + 1.0f);
}

// ---------------------------------------------------------------------------
// A1: g[b,h] = hidden[b,:]@W[:,h] + bias[h]   (atomic over 4 d-chunks)
// grid 32*2*4 = 256 blocks x 256 thr
__global__ void k_dens1(const float* __restrict__ hs, const float* __restrict__ W,
                        const float* __restrict__ bias, float* __restrict__ g) {
    int bi = blockIdx.x;
    int dc = bi & 3, hb = (bi >> 2) & 1, b = bi >> 3;
    int h = hb * 256 + threadIdx.x;
    float s = (dc == 0) ? bias[h] : 0.0f;
    int d0 = dc * 128;
    #pragma unroll 4
    for (int d = 0; d < 128; ++d)
        s = fmaf(hs[b * DD + d0 + d], W[(size_t)(d0 + d) * HH + h], s);
    atomicAdd(&g[b * HH + h], s);
}

// A2: cvec[b,k] = g[b,:]@Wa[:,k] + ba[k]   (atomic over 4 h-chunks)
// grid 32*2*4 = 256 blocks x 256 thr
__global__ void k_cvec(const float* __restrict__ g, const float* __restrict__ Wa,
                       const float* __restrict__ ba, float* __restrict__ cvec) {
    int bi = blockIdx.x;
    int hc = bi & 3, kb = (bi >> 2) & 1, b = bi >> 3;
    int k = kb * 256 + threadIdx.x;
    float s = (hc == 0) ? ba[k] : 0.0f;
    int h0 = hc * 128;
    #pragma unroll 4
    for (int h = 0; h < 128; ++h)
        s = fmaf(g[b * HH + h0 + h], Wa[(size_t)(h0 + h) * HH + k], s);
    atomicAdd(&cvec[b * HH + k], s);
}

// A3: UWaT[n][d] = bf16( sum_h U[d,h]*Wa[h,n] )  -- transposed, B-fragment friendly
// grid 128 blocks (4 d-rows each) x 256 thr (each thread: n=tid and n=tid+256)
__global__ void k_uwa(const float* __restrict__ U, const float* __restrict__ Wa,
                      unsigned short* __restrict__ UWaT) {
    int d0 = blockIdx.x * 4;
    int tid = threadIdx.x;
    __shared__ float Us[4][DD];
    #pragma unroll
    for (int i = 0; i < 8; ++i) {
        int idx = i * 256 + tid;
        Us[idx >> 9][idx & 511] = U[(size_t)(d0 + (idx >> 9)) * HH + (idx & 511)];
    }
    __syncthreads();
    float acc[4][2] = {};
    #pragma unroll 4
    for (int h = 0; h < DD; ++h) {
        float w0 = Wa[(size_t)h * HH + tid];
        float w1 = Wa[(size_t)h * HH + 256 + tid];
        #pragma unroll
        for (int dd = 0; dd < 4; ++dd) {
            float u = Us[dd][h];
            acc[dd][0] = fmaf(u, w0, acc[dd][0]);
            acc[dd][1] = fmaf(u, w1, acc[dd][1]);
        }
    }
    #pragma unroll
    for (int dd = 0; dd < 4; ++dd) {
        UWaT[(size_t)tid * DD + d0 + dd] = f2bf_rne(acc[dd][0]);
        UWaT[(size_t)(tid + 256) * DD + d0 + dd] = f2bf_rne(acc[dd][1]);
    }
}

// ---------------------------------------------------------------------------
// B: the big GEMM + tanh*V epilogue.
// Tile 128(M) x 128(N), BK=64, 256 thr = 4 waves in 2x2, each wave 64x64 via
// 4x4 frags of mfma_f32_16x16x32_bf16. A staged fp32->bf16 inline; B is bf16
// already (UWaT). grid 4096: n_tile fastest so 4 siblings share A via L2/L3.
#define LDA 72   // BK + 8 pad: frag ds_read_b128 lands 2-way max (free)

__global__ void __launch_bounds__(256) k_gemm_tanh(
    const float* __restrict__ e, const unsigned short* __restrict__ Bt,
    const float* __restrict__ cvec, const float* __restrict__ V,
    float* __restrict__ cij) {
    int tid = threadIdx.x;
    int n_tile = blockIdx.x & 3;
    int m_tile = blockIdx.x >> 2;
    int m0 = m_tile << 7;
    int n0 = n_tile << 7;
    int lane = tid & 63, wid = tid >> 6;
    int wm = (wid >> 1) << 6;   // 0 / 64
    int wn = (wid & 1) << 6;
    int lcol = lane & 15, q = lane >> 4;

    __shared__ __align__(16) unsigned short As[128 * LDA];
    __shared__ __align__(16) unsigned short Bs[128 * LDA];

    f32x4 acc[4][4] = {};

    const float* Abase = e + (size_t)m0 * DD;
    const unsigned short* Bbase = Bt + (size_t)n0 * DD;

    for (int k0 = 0; k0 < DD; k0 += 64) {
        // stage A: 128 x 64 fp32 -> bf16 (truncation). 2048 float4 / 256 thr.
        #pragma unroll
        for (int it = 0; it < 8; ++it) {
            int idx = it * 256 + tid;
            int row = idx >> 4, c4 = idx & 15;
            float4 v = *(const float4*)(Abase + (size_t)row * DD + k0 + c4 * 4);
            uint2 w;
            w.x = pack_bf16_trunc(v.x, v.y);
            w.y = pack_bf16_trunc(v.z, v.w);
            *(uint2*)&As[row * LDA + c4 * 4] = w;
        }
        // stage B: 128 x 64 bf16 direct. 1024 16B-units / 256 thr.
        #pragma unroll
        for (int it = 0; it < 4; ++it) {
            int idx = it * 256 + tid;
            int row = idx >> 3, c8 = idx & 7;
            int4 v = *(const int4*)(Bbase + (size_t)row * DD + k0 + c8 * 8);
            *(int4*)&Bs[row * LDA + c8 * 8] = v;
        }
        __syncthreads();
        #pragma unroll
        for (int ks = 0; ks < 64; ks += 32) {
            s16x8 af[4], bfr[4];
            #pragma unroll
            for (int i = 0; i < 4; ++i)
                af[i] = *(const s16x8*)&As[(wm + i * 16 + lcol) * LDA + ks + q * 8];
            #pragma unroll
            for (int j = 0; j < 4; ++j)
                bfr[j] = *(const s16x8*)&Bs[(wn + j * 16 + lcol) * LDA + ks + q * 8];
            #pragma unroll
            for (int i = 0; i < 4; ++i)
                #pragma unroll
                for (int j = 0; j < 4; ++j)
                    acc[i][j] = __builtin_amdgcn_mfma_f32_16x16x32_bf16(
                        af[i], bfr[j], acc[i][j], 0, 0, 0);
        }
        __syncthreads();
    }

    // Epilogue: cij[row] += sum_{h in this 128-col block} tanh(acc + cvec[b,h]) * V[h]
    // C/D layout: col = lane&15, row = (lane>>4)*4 + reg   [m89/m91 verified]
    int b = m0 >> 12;  // row / 4096
    float cvv[4], Vv[4];
    #pragma unroll
    for (int j = 0; j < 4; ++j) {
        int h = n0 + wn + j * 16 + lcol;
        cvv[j] = cvec[b * HH + h];
        Vv[j] = V[h];
    }
    #pragma unroll
    for (int i = 0; i < 4; ++i) {
        #pragma unroll
        for (int r = 0; r < 4; ++r) {
            float s = 0.0f;
            #pragma unroll
            for (int j = 0; j < 4; ++j) {
                float pre = acc[i][j][r] + cvv[j];
                s = fmaf(tanh_fast(pre), Vv[j], s);
            }
            // reduce the 16 lanes (lane&15) sharing this output row
            s += __shfl_xor(s, 1);
            s += __shfl_xor(s, 2);
            s += __shfl_xor(s, 4);
            s += __shfl_xor(s, 8);
            if (lcol == 0)
                atomicAdd(&cij[m0 + wm + i * 16 + q * 4 + r], s);
        }
    }
}

// ---------------------------------------------------------------------------
// C1: softmax over T per batch. 32 blocks x 256 thr.
__global__ void k_softmax(const float* __restrict__ cij, float* __restrict__ alphas) {
    int b = blockIdx.x, tid = threadIdx.x;
    const float* row = cij + (size_t)b * TT;
    __shared__ float red[4];
    float m = -1e30f;
    for (int t = tid; t < TT; t += 256) m = fmaxf(m, row[t]);
    #pragma unroll
    for (int o = 1; o < 64; o <<= 1) m = fmaxf(m, __shfl_xor(m, o));
    if ((tid & 63) == 0) red[tid >> 6] = m;
    __syncthreads();
    m = fmaxf(fmaxf(red[0], red[1]), fmaxf(red[2], red[3]));
    __syncthreads();
    float sum = 0.0f;
    for (int t = tid; t < TT; t += 256) sum += __expf(row[t] - m);
    #pragma unroll
    for (int o = 1; o < 64; o <<= 1) sum += __shfl_xor(sum, o);
    if ((tid & 63) == 0) red[tid >> 6] = sum;
    __syncthreads();
    float inv = 1.0f / (red[0] + red[1] + red[2] + red[3]);
    for (int t = tid; t < TT; t += 256)
        alphas[(size_t)b * TT + t] = __expf(row[t] - m) * inv;
}

// C2: out[b,d] = sum_t alphas[b,t] * e[b,t,d]. Memory-bound 268MB stream.
// grid 32*32 blocks x 256 thr; each block: 128 t's, threads = 2 rows x 128 float4.
__global__ void k_wsum(const float* __restrict__ e, const float* __restrict__ alphas,
                       float* __restrict__ out) {
    int b = blockIdx.x >> 5;
    int t0 = (blockIdx.x & 31) * 128;
    int tid = threadIdx.x;
    int half = tid >> 7, f4 = tid & 127;
    const float* base = e + (size_t)b * TT * DD;
    float4 acc = {0.0f, 0.0f, 0.0f, 0.0f};
    for (int it = 0; it < 64; ++it) {
        int t = t0 + it * 2 + half;
        float a = alphas[(size_t)b * TT + t];
        float4 v = *(const float4*)(base + (size_t)t * DD + f4 * 4);
        acc.x = fmaf(a, v.x, acc.x);
        acc.y = fmaf(a, v.y, acc.y);
        acc.z = fmaf(a, v.z, acc.z);
        acc.w = fmaf(a, v.w, acc.w);
    }
    float* o = out + b * DD + f4 * 4;
    atomicAdd(o + 0, acc.x);
    atomicAdd(o + 1, acc.y);
    atomicAdd(o + 2, acc.z);
    atomicAdd(o + 3, acc.w);
}

// ---------------------------------------------------------------------------
extern "C" void kernel_launch(void* const* d_in, const int* in_sizes, int n_in,
                              void* d_out, int out_size, void* d_ws, size_t ws_size,
                              hipStream_t stream) {
    const float* hs   = (const float*)d_in[0];   // [32,512]
    const float* e    = (const float*)d_in[1];   // [32,4096,512]
    const float* W    = (const float*)d_in[2];   // [512,512]
    const float* U    = (const float*)d_in[3];   // [512,512]
    const float* V    = (const float*)d_in[4];   // [512]
    const float* bias = (const float*)d_in[5];   // [512]
    const float* Wa   = (const float*)d_in[6];   // [512,512]
    const float* ba   = (const float*)d_in[7];   // [512]

    float* out    = (float*)d_out;               // [32,512] then alphas [32,4096]
    float* alphas = out + BB * DD;

    // workspace layout
    float*          cij  = (float*)d_ws;                              // 512 KB
    float*          g    = (float*)((char*)d_ws + 524288);            // 64 KB
    float*          cvec = (float*)((char*)d_ws + 589824);            // 64 KB
    unsigned short* Bt   = (unsigned short*)((char*)d_ws + 655360);   // 512 KB bf16

    // zero atomic accumulators (ws+out are poisoned 0xAA before every launch)
    hipMemsetAsync(d_ws, 0, 655360, stream);              // cij + g + cvec
    hipMemsetAsync(d_out, 0, BB * DD * sizeof(float), stream);

    k_dens1<<<256, 256, 0, stream>>>(hs, W, bias, g);
    k_cvec<<<256, 256, 0, stream>>>(g, Wa, ba, cvec);
    k_uwa<<<128, 256, 0, stream>>>(U, Wa, Bt);
    k_gemm_tanh<<<4096, 256, 0, stream>>>(e, Bt, cvec, V, cij);
    k_softmax<<<BB, 256, 0, stream>>>(cij, alphas);
    k_wsum<<<BB * 32, 256, 0, stream>>>(e, alphas, out);
}